// Round 1
// baseline (1120.752 us; speedup 1.0000x reference)
//
#include <hip/hip_runtime.h>

#define HASH_BITS 20
#define HASH_SIZE (1u << HASH_BITS)
#define HASH_MASK (HASH_SIZE - 1)
#define EMPTY_KEY 0xFFFFFFFFu
#define CH 256
#define TM 16

// ---------------- hash build ----------------
__global__ void hash_insert_k(const int* __restrict__ coords, int n,
                              unsigned* __restrict__ hkeys, int* __restrict__ hvals) {
    int i = blockIdx.x * blockDim.x + threadIdx.x;
    if (i >= n) return;
    unsigned cx = (unsigned)(coords[3 * i + 0] + 1);
    unsigned cy = (unsigned)(coords[3 * i + 1] + 1);
    unsigned cz = (unsigned)(coords[3 * i + 2] + 1);
    unsigned key = (cx * 258u + cy) * 258u + cz;
    unsigned h = (key * 2654435761u) & HASH_MASK;
    while (true) {
        unsigned prev = atomicCAS(&hkeys[h], EMPTY_KEY, key);
        if (prev == EMPTY_KEY) { hvals[h] = i; return; }
        h = (h + 1) & HASH_MASK;
    }
}

// ---------------- neighbor pair list (non-center offsets only) ----------------
__global__ void neighbor_pairs_k(const int* __restrict__ coords, int n,
                                 const unsigned* __restrict__ hkeys,
                                 const int* __restrict__ hvals,
                                 int2* __restrict__ pairs, int* __restrict__ pcount) {
    int t = blockIdx.x * blockDim.x + threadIdx.x;
    if (t >= n * 27) return;
    int i = t / 27, k = t % 27;
    if (k == 13) return;  // center: handled densely (always self)
    int dx = k / 9 - 1, dy = (k / 3) % 3 - 1, dz = k % 3 - 1;
    unsigned cx = (unsigned)(coords[3 * i + 0] + 1 + dx);
    unsigned cy = (unsigned)(coords[3 * i + 1] + 1 + dy);
    unsigned cz = (unsigned)(coords[3 * i + 2] + 1 + dz);
    unsigned key = (cx * 258u + cy) * 258u + cz;
    unsigned h = (key * 2654435761u) & HASH_MASK;
    while (true) {
        unsigned kk = hkeys[h];
        if (kk == key) {
            int j = hvals[h];
            int pos = atomicAdd(pcount, 1);
            pairs[pos] = make_int2(i, j | (k << 20));
            return;
        }
        if (kk == EMPTY_KEY) return;
        h = (h + 1) & HASH_MASK;
    }
}

// ---------------- layer 1: Cin=2 -> 256 ----------------
__global__ void dense1_k(const float* __restrict__ x, const float* __restrict__ Wc,
                         float* __restrict__ out, int n) {
    int t = blockIdx.x * blockDim.x + threadIdx.x;
    if (t >= n * CH) return;
    int i = t >> 8, co = t & 255;
    float2 xv = *reinterpret_cast<const float2*>(x + 2 * i);
    out[t] = fmaf(xv.x, Wc[co], xv.y * Wc[CH + co]);
}

__global__ void sparse1_k(const float* __restrict__ x, const float* __restrict__ W,
                          float* __restrict__ out, const int2* __restrict__ pairs,
                          const int* __restrict__ pcount) {
    int cnt = *pcount;
    int co = threadIdx.x;
    for (int m = blockIdx.x; m < cnt; m += gridDim.x) {
        int2 p = pairs[m];
        int i = p.x, j = p.y & 0xFFFFF, k = p.y >> 20;
        const float* Wk = W + (size_t)k * 2 * CH;
        float2 xv = *reinterpret_cast<const float2*>(x + 2 * j);
        atomicAdd(&out[(size_t)i * CH + co], fmaf(xv.x, Wk[co], xv.y * Wk[CH + co]));
    }
}

// ---------------- mid layers: 256 -> 256 ----------------
__global__ void dense_mid_k(const float* __restrict__ x, const float* __restrict__ Wc,
                            float* __restrict__ out, int n) {
    __shared__ float xs[TM][CH];
    int co = threadIdx.x;
    int i0 = blockIdx.x * TM;
#pragma unroll
    for (int m = 0; m < TM; ++m) {
        int i = i0 + m;
        xs[m][co] = (i < n) ? x[(size_t)i * CH + co] : 0.f;
    }
    __syncthreads();
    float acc[TM];
#pragma unroll
    for (int m = 0; m < TM; ++m) acc[m] = 0.f;
    for (int ci = 0; ci < CH; ci += 4) {
        float w0 = Wc[(ci + 0) * CH + co];
        float w1 = Wc[(ci + 1) * CH + co];
        float w2 = Wc[(ci + 2) * CH + co];
        float w3 = Wc[(ci + 3) * CH + co];
#pragma unroll
        for (int m = 0; m < TM; ++m) {
            float4 xv = *reinterpret_cast<const float4*>(&xs[m][ci]);
            acc[m] = fmaf(xv.x, w0, acc[m]);
            acc[m] = fmaf(xv.y, w1, acc[m]);
            acc[m] = fmaf(xv.z, w2, acc[m]);
            acc[m] = fmaf(xv.w, w3, acc[m]);
        }
    }
#pragma unroll
    for (int m = 0; m < TM; ++m) {
        int i = i0 + m;
        if (i < n) out[(size_t)i * CH + co] = acc[m];
    }
}

__global__ void sparse_mid_k(const float* __restrict__ x, const float* __restrict__ W,
                             float* __restrict__ out, const int2* __restrict__ pairs,
                             const int* __restrict__ pcount) {
    __shared__ float xs[CH];
    int cnt = *pcount;
    int co = threadIdx.x;
    for (int m = blockIdx.x; m < cnt; m += gridDim.x) {
        int2 p = pairs[m];
        int i = p.x, j = p.y & 0xFFFFF, k = p.y >> 20;
        xs[co] = x[(size_t)j * CH + co];
        __syncthreads();
        const float* Wk = W + (size_t)k * CH * CH;
        float acc = 0.f;
        for (int ci = 0; ci < CH; ci += 4) {
            float4 xv = *reinterpret_cast<const float4*>(&xs[ci]);
            acc = fmaf(xv.x, Wk[(ci + 0) * CH + co], acc);
            acc = fmaf(xv.y, Wk[(ci + 1) * CH + co], acc);
            acc = fmaf(xv.z, Wk[(ci + 2) * CH + co], acc);
            acc = fmaf(xv.w, Wk[(ci + 3) * CH + co], acc);
        }
        atomicAdd(&out[(size_t)i * CH + co], acc);
        __syncthreads();
    }
}

// ---------------- layer 4: 256 -> 2 ----------------
__device__ inline float wave_sum(float v) {
    for (int off = 32; off; off >>= 1) v += __shfl_xor(v, off);
    return v;
}

__global__ void dense4_k(const float* __restrict__ x, const float* __restrict__ Wc,
                         float* __restrict__ out, int n) {
    int wid = threadIdx.x >> 6, lane = threadIdx.x & 63;
    int i = blockIdx.x * 4 + wid;
    if (i >= n) return;
    float4 xv = *reinterpret_cast<const float4*>(x + (size_t)i * CH + lane * 4);
    float4 w0 = *reinterpret_cast<const float4*>(Wc + lane * 8);
    float4 w1 = *reinterpret_cast<const float4*>(Wc + lane * 8 + 4);
    float a0 = xv.x * w0.x + xv.y * w0.z + xv.z * w1.x + xv.w * w1.z;
    float a1 = xv.x * w0.y + xv.y * w0.w + xv.z * w1.y + xv.w * w1.w;
    a0 = wave_sum(a0);
    a1 = wave_sum(a1);
    if (lane == 0) { out[2 * i] = a0; out[2 * i + 1] = a1; }
}

__global__ void sparse4_k(const float* __restrict__ x, const float* __restrict__ W,
                          float* __restrict__ out, const int2* __restrict__ pairs,
                          const int* __restrict__ pcount) {
    int cnt = *pcount;
    int lane = threadIdx.x & 63;
    for (int m = blockIdx.x; m < cnt; m += gridDim.x) {
        int2 p = pairs[m];
        int i = p.x, j = p.y & 0xFFFFF, k = p.y >> 20;
        const float* Wk = W + (size_t)k * CH * 2;
        float4 xv = *reinterpret_cast<const float4*>(x + (size_t)j * CH + lane * 4);
        float4 w0 = *reinterpret_cast<const float4*>(Wk + lane * 8);
        float4 w1 = *reinterpret_cast<const float4*>(Wk + lane * 8 + 4);
        float a0 = xv.x * w0.x + xv.y * w0.z + xv.z * w1.x + xv.w * w1.z;
        float a1 = xv.x * w0.y + xv.y * w0.w + xv.z * w1.y + xv.w * w1.w;
        a0 = wave_sum(a0);
        a1 = wave_sum(a1);
        if (lane == 0) {
            atomicAdd(&out[2 * i], a0);
            atomicAdd(&out[2 * i + 1], a1);
        }
    }
}

extern "C" void kernel_launch(void* const* d_in, const int* in_sizes, int n_in,
                              void* d_out, int out_size, void* d_ws, size_t ws_size,
                              hipStream_t stream) {
    const int* coords = (const int*)d_in[0];
    const float* feats = (const float*)d_in[1];
    const float* W1 = (const float*)d_in[2];
    const float* W2 = (const float*)d_in[3];
    const float* W3 = (const float*)d_in[4];
    const float* W4 = (const float*)d_in[5];
    float* out = (float*)d_out;
    int n = in_sizes[0] / 3;

    char* ws = (char*)d_ws;
    unsigned* hkeys = (unsigned*)ws;  ws += (size_t)HASH_SIZE * 4;
    int* hvals = (int*)ws;            ws += (size_t)HASH_SIZE * 4;
    int* pcount = (int*)ws;           ws += 256;
    int2* pairs = (int2*)ws;          ws += (size_t)26 * n * 8;
    float* x1 = (float*)ws;           ws += (size_t)n * CH * 4;
    float* x2 = (float*)ws;           ws += (size_t)n * CH * 4;

    hipMemsetAsync(hkeys, 0xFF, (size_t)HASH_SIZE * 4, stream);
    hipMemsetAsync(pcount, 0, 4, stream);

    hash_insert_k<<<(n + 255) / 256, 256, 0, stream>>>(coords, n, hkeys, hvals);
    neighbor_pairs_k<<<(n * 27 + 255) / 256, 256, 0, stream>>>(coords, n, hkeys, hvals,
                                                               pairs, pcount);

    // layer 1: 2 -> 256
    dense1_k<<<(n * CH + 255) / 256, 256, 0, stream>>>(feats, W1 + 13 * 2 * CH, x1, n);
    sparse1_k<<<1024, 256, 0, stream>>>(feats, W1, x1, pairs, pcount);

    // layer 2: 256 -> 256
    dense_mid_k<<<(n + TM - 1) / TM, 256, 0, stream>>>(x1, W2 + 13 * CH * CH, x2, n);
    sparse_mid_k<<<2048, 256, 0, stream>>>(x1, W2, x2, pairs, pcount);

    // layer 3: 256 -> 256
    dense_mid_k<<<(n + TM - 1) / TM, 256, 0, stream>>>(x2, W3 + 13 * CH * CH, x1, n);
    sparse_mid_k<<<2048, 256, 0, stream>>>(x2, W3, x1, pairs, pcount);

    // layer 4: 256 -> 2
    dense4_k<<<(n + 3) / 4, 256, 0, stream>>>(x1, W4 + 13 * CH * 2, out, n);
    sparse4_k<<<2048, 64, 0, stream>>>(x1, W4, out, pairs, pcount);
}

// Round 2
// 427.664 us; speedup vs baseline: 2.6206x; 2.6206x over previous
//
#include <hip/hip_runtime.h>

#define HASH_BITS 20
#define HASH_SIZE (1u << HASH_BITS)
#define HASH_MASK (HASH_SIZE - 1)
#define EMPTY_KEY 0xFFFFFFFFu
#define CH 256
#define PCH 16  // pairs per chunk in bucketed sparse kernels

typedef __attribute__((ext_vector_type(8))) short short8;
typedef __attribute__((ext_vector_type(4))) float floatx4;

// split fp32 -> bf16 hi + bf16 lo (x ~= hi + lo, each RTN-even)
__device__ inline void bf16_split(float x, unsigned short& hi, unsigned short& lo) {
    unsigned u = __float_as_uint(x);
    unsigned r = u + (0x7FFFu + ((u >> 16) & 1u));
    hi = (unsigned short)(r >> 16);
    float hif = __uint_as_float(((unsigned)hi) << 16);
    float res = x - hif;
    unsigned v = __float_as_uint(res);
    unsigned rv = v + (0x7FFFu + ((v >> 16) & 1u));
    lo = (unsigned short)(rv >> 16);
}

// ---------------- hash build ----------------
__global__ void hash_insert_k(const int* __restrict__ coords, int n,
                              unsigned* __restrict__ hkeys, int* __restrict__ hvals) {
    int i = blockIdx.x * blockDim.x + threadIdx.x;
    if (i >= n) return;
    unsigned cx = (unsigned)(coords[3 * i + 0] + 1);
    unsigned cy = (unsigned)(coords[3 * i + 1] + 1);
    unsigned cz = (unsigned)(coords[3 * i + 2] + 1);
    unsigned key = (cx * 258u + cy) * 258u + cz;
    unsigned h = (key * 2654435761u) & HASH_MASK;
    while (true) {
        unsigned prev = atomicCAS(&hkeys[h], EMPTY_KEY, key);
        if (prev == EMPTY_KEY) { hvals[h] = i; return; }
        h = (h + 1) & HASH_MASK;
    }
}

// ---------------- neighbor pairs, bucketed by offset k ----------------
__global__ void neighbor_buckets_k(const int* __restrict__ coords, int n,
                                   const unsigned* __restrict__ hkeys,
                                   const int* __restrict__ hvals,
                                   int2* __restrict__ buckets, int* __restrict__ kcount) {
    int t = blockIdx.x * blockDim.x + threadIdx.x;
    if (t >= n * 27) return;
    int i = t / 27, k = t % 27;
    if (k == 13) return;  // center handled densely
    int dx = k / 9 - 1, dy = (k / 3) % 3 - 1, dz = k % 3 - 1;
    unsigned cx = (unsigned)(coords[3 * i + 0] + 1 + dx);
    unsigned cy = (unsigned)(coords[3 * i + 1] + 1 + dy);
    unsigned cz = (unsigned)(coords[3 * i + 2] + 1 + dz);
    unsigned key = (cx * 258u + cy) * 258u + cz;
    unsigned h = (key * 2654435761u) & HASH_MASK;
    while (true) {
        unsigned kk = hkeys[h];
        if (kk == key) {
            int j = hvals[h];
            int pos = atomicAdd(&kcount[k], 1);
            buckets[(size_t)k * n + pos] = make_int2(i, j);
            return;
        }
        if (kk == EMPTY_KEY) return;
        h = (h + 1) & HASH_MASK;
    }
}

// ---------------- chunk descriptors: (start, k<<8|len) per <=PCH-pair chunk ----------------
__global__ void chunk_desc_k(const int* __restrict__ kcount, int n,
                             int2* __restrict__ desc, int* __restrict__ nchunks) {
    __shared__ int offs[28];
    int t = threadIdx.x;
    if (t == 0) {
        int acc = 0;
        for (int k = 0; k < 27; ++k) { offs[k] = acc; acc += (kcount[k] + PCH - 1) / PCH; }
        offs[27] = acc;
        *nchunks = acc;
    }
    __syncthreads();
    if (t < 27) {
        int cnt = kcount[t];
        int o = offs[t];
        for (int c = 0; c * PCH < cnt; ++c) {
            int len = min(PCH, cnt - c * PCH);
            desc[o + c] = make_int2(t * n + c * PCH, (t << 8) | len);
        }
    }
}

// ---------------- pre-split center W slice into MFMA-fragment-ordered bf16 image ----------
// image layout: [kk(8)][nt(16)][lane(64)][j(8)] shorts; k = kk*32 + (lane>>4)*8 + j,
// col = nt*16 + (lane&15)
__global__ void prep_w_k(const float* __restrict__ W, unsigned short* __restrict__ Whi,
                         unsigned short* __restrict__ Wlo) {
    int t = blockIdx.x * 256 + threadIdx.x;
    if (t >= 65536) return;
    int k = t >> 8, col = t & 255;
    float w = W[13 * 65536 + t];
    unsigned short hb, lb;
    bf16_split(w, hb, lb);
    int kk = k >> 5, kg = (k >> 3) & 3, j = k & 7, nt = col >> 4, lcol = col & 15;
    int idx = ((kk * 16 + nt) * 64 + (kg * 16 + lcol)) * 8 + j;
    Whi[idx] = hb;
    Wlo[idx] = lb;
}

// ---------------- layer 1: Cin=2 -> 256, dense center ----------------
__global__ void dense1_k(const float* __restrict__ x, const float* __restrict__ Wc,
                         float* __restrict__ out, int n) {
    int t = blockIdx.x * blockDim.x + threadIdx.x;
    if (t >= n * CH) return;
    int i = t >> 8, co = t & 255;
    float2 xv = *reinterpret_cast<const float2*>(x + 2 * i);
    out[t] = fmaf(xv.x, Wc[co], xv.y * Wc[CH + co]);
}

__global__ void sparse1b_k(const float* __restrict__ feats, const float* __restrict__ W1,
                           float* __restrict__ out, const int2* __restrict__ buckets,
                           const int2* __restrict__ desc, const int* __restrict__ nchunks) {
    __shared__ float xs[PCH][2];
    __shared__ int ii[PCH];
    int nc = *nchunks;
    int t = threadIdx.x;
    for (int m = blockIdx.x; m < nc; m += gridDim.x) {
        int2 d = desc[m];
        int k = d.y >> 8, len = d.y & 255;
        if (t < PCH) {
            if (t < len) {
                int2 pr = buckets[d.x + t];
                ii[t] = pr.x;
                xs[t][0] = feats[2 * pr.y];
                xs[t][1] = feats[2 * pr.y + 1];
            } else {
                ii[t] = -1;
                xs[t][0] = 0.f; xs[t][1] = 0.f;
            }
        }
        __syncthreads();
        const float* Wk = W1 + (size_t)k * 2 * CH;
        float w0 = Wk[t], w1 = Wk[CH + t];
#pragma unroll
        for (int p = 0; p < PCH; ++p) {
            int i = ii[p];
            if (i >= 0) atomicAdd(&out[(size_t)i * CH + t], fmaf(xs[p][0], w0, xs[p][1] * w1));
        }
        __syncthreads();
    }
}

// ---------------- mid layers dense center: split-bf16 3-pass MFMA ----------------
__global__ __launch_bounds__(256) void dense_mid_mfma_k(
        const float* __restrict__ x,
        const unsigned short* __restrict__ Whi,
        const unsigned short* __restrict__ Wlo,
        float* __restrict__ out, int n) {
    __shared__ unsigned short As_hi[4 * 64 * 8];
    __shared__ unsigned short As_lo[4 * 64 * 8];
    __shared__ unsigned short Bs_hi[16 * 64 * 8];
    __shared__ unsigned short Bs_lo[16 * 64 * 8];
    int t = threadIdx.x;
    int wid = t >> 6, lane = t & 63;
    int i0 = blockIdx.x * 64;

    floatx4 acc[4][4];
#pragma unroll
    for (int a = 0; a < 4; ++a)
#pragma unroll
        for (int b = 0; b < 4; ++b) acc[a][b] = floatx4{0.f, 0.f, 0.f, 0.f};

    int ar = t >> 2;   // row 0..63 in tile
    int akg = t & 3;   // k-group
    int abase = ((ar >> 4) * 64 + (akg * 16 + (ar & 15))) * 8;
    const float* xrow = x + (size_t)(i0 + ar) * CH + akg * 8;
    bool arow_ok = (i0 + ar) < n;

    for (int kk = 0; kk < 8; ++kk) {
        // ---- stage A: load 8 fp32, split to hi/lo, write fragment-ordered ----
        float xa[8];
        if (arow_ok) {
            floatx4 v0 = *(const floatx4*)(xrow + kk * 32);
            floatx4 v1 = *(const floatx4*)(xrow + kk * 32 + 4);
            xa[0] = v0.x; xa[1] = v0.y; xa[2] = v0.z; xa[3] = v0.w;
            xa[4] = v1.x; xa[5] = v1.y; xa[6] = v1.z; xa[7] = v1.w;
        } else {
#pragma unroll
            for (int q = 0; q < 8; ++q) xa[q] = 0.f;
        }
        unsigned short h[8], l[8];
#pragma unroll
        for (int q = 0; q < 8; ++q) bf16_split(xa[q], h[q], l[q]);
        uint4 hv, lv;
        hv.x = (unsigned)h[0] | ((unsigned)h[1] << 16);
        hv.y = (unsigned)h[2] | ((unsigned)h[3] << 16);
        hv.z = (unsigned)h[4] | ((unsigned)h[5] << 16);
        hv.w = (unsigned)h[6] | ((unsigned)h[7] << 16);
        lv.x = (unsigned)l[0] | ((unsigned)l[1] << 16);
        lv.y = (unsigned)l[2] | ((unsigned)l[3] << 16);
        lv.z = (unsigned)l[4] | ((unsigned)l[5] << 16);
        lv.w = (unsigned)l[6] | ((unsigned)l[7] << 16);
        *(uint4*)&As_hi[abase] = hv;
        *(uint4*)&As_lo[abase] = lv;
        // ---- stage B: linear copy of pre-ordered slab (16KB hi + 16KB lo) ----
        {
            const uint4* gh = (const uint4*)(Whi + kk * 8192);
            const uint4* gl = (const uint4*)(Wlo + kk * 8192);
            uint4* sh = (uint4*)Bs_hi;
            uint4* sl = (uint4*)Bs_lo;
#pragma unroll
            for (int c = 0; c < 4; ++c) {
                sh[t + c * 256] = gh[t + c * 256];
                sl[t + c * 256] = gl[t + c * 256];
            }
        }
        __syncthreads();
        short8 ah[4], al[4], bh[4], bl[4];
#pragma unroll
        for (int mt = 0; mt < 4; ++mt) {
            ah[mt] = *(const short8*)&As_hi[(mt * 64 + lane) * 8];
            al[mt] = *(const short8*)&As_lo[(mt * 64 + lane) * 8];
        }
#pragma unroll
        for (int nt = 0; nt < 4; ++nt) {
            int g = ((wid * 4 + nt) * 64 + lane) * 8;
            bh[nt] = *(const short8*)&Bs_hi[g];
            bl[nt] = *(const short8*)&Bs_lo[g];
        }
#pragma unroll
        for (int mt = 0; mt < 4; ++mt)
#pragma unroll
            for (int nt = 0; nt < 4; ++nt) {
                acc[mt][nt] = __builtin_amdgcn_mfma_f32_16x16x32_bf16(ah[mt], bh[nt], acc[mt][nt], 0, 0, 0);
                acc[mt][nt] = __builtin_amdgcn_mfma_f32_16x16x32_bf16(al[mt], bh[nt], acc[mt][nt], 0, 0, 0);
                acc[mt][nt] = __builtin_amdgcn_mfma_f32_16x16x32_bf16(ah[mt], bl[nt], acc[mt][nt], 0, 0, 0);
            }
        __syncthreads();
    }
    // epilogue: D row=(lane>>4)*4+reg, col=lane&15
    int r0 = (lane >> 4) * 4, c0 = lane & 15;
#pragma unroll
    for (int mt = 0; mt < 4; ++mt)
#pragma unroll
        for (int r = 0; r < 4; ++r) {
            int row = i0 + mt * 16 + r0 + r;
            if (row < n) {
#pragma unroll
                for (int nt = 0; nt < 4; ++nt)
                    out[(size_t)row * CH + wid * 64 + nt * 16 + c0] = acc[mt][nt][r];
            }
        }
}

// ---------------- mid layers sparse: 16 pairs/chunk share one W slice ----------------
__global__ void sparse_mid2_k(const float* __restrict__ x, const float* __restrict__ W,
                              float* __restrict__ out, const int2* __restrict__ buckets,
                              const int2* __restrict__ desc, const int* __restrict__ nchunks) {
    __shared__ float xs[PCH][CH];
    __shared__ int ii[PCH];
    int nc = *nchunks;
    int t = threadIdx.x;
    for (int m = blockIdx.x; m < nc; m += gridDim.x) {
        int2 d = desc[m];
        int k = d.y >> 8, len = d.y & 255;
        int p = t >> 4, cb = (t & 15) * 16;
        if (p < len) {
            int2 pr = buckets[d.x + p];
            if ((t & 15) == 0) ii[p] = pr.x;
            const float* src = x + (size_t)pr.y * CH + cb;
            *(floatx4*)&xs[p][cb + 0]  = *(const floatx4*)(src + 0);
            *(floatx4*)&xs[p][cb + 4]  = *(const floatx4*)(src + 4);
            *(floatx4*)&xs[p][cb + 8]  = *(const floatx4*)(src + 8);
            *(floatx4*)&xs[p][cb + 12] = *(const floatx4*)(src + 12);
        } else {
            if ((t & 15) == 0) ii[p] = -1;
            floatx4 z = {0.f, 0.f, 0.f, 0.f};
            *(floatx4*)&xs[p][cb + 0] = z;
            *(floatx4*)&xs[p][cb + 4] = z;
            *(floatx4*)&xs[p][cb + 8] = z;
            *(floatx4*)&xs[p][cb + 12] = z;
        }
        __syncthreads();
        const float* Wk = W + (size_t)k * CH * CH;
        float a[PCH];
#pragma unroll
        for (int q = 0; q < PCH; ++q) a[q] = 0.f;
        for (int ci = 0; ci < CH; ci += 4) {
            float w0 = Wk[(ci + 0) * CH + t];
            float w1 = Wk[(ci + 1) * CH + t];
            float w2 = Wk[(ci + 2) * CH + t];
            float w3 = Wk[(ci + 3) * CH + t];
#pragma unroll
            for (int q = 0; q < PCH; ++q) {
                floatx4 xv = *(const floatx4*)&xs[q][ci];
                a[q] = fmaf(xv.x, w0, a[q]);
                a[q] = fmaf(xv.y, w1, a[q]);
                a[q] = fmaf(xv.z, w2, a[q]);
                a[q] = fmaf(xv.w, w3, a[q]);
            }
        }
#pragma unroll
        for (int q = 0; q < PCH; ++q) {
            int i = ii[q];
            if (i >= 0) atomicAdd(&out[(size_t)i * CH + t], a[q]);
        }
        __syncthreads();
    }
}

// ---------------- layer 4: 256 -> 2 ----------------
__device__ inline float wave_sum(float v) {
    for (int off = 32; off; off >>= 1) v += __shfl_xor(v, off);
    return v;
}

__global__ void dense4_k(const float* __restrict__ x, const float* __restrict__ Wc,
                         float* __restrict__ out, int n) {
    int wid = threadIdx.x >> 6, lane = threadIdx.x & 63;
    int i = blockIdx.x * 4 + wid;
    if (i >= n) return;
    floatx4 xv = *reinterpret_cast<const floatx4*>(x + (size_t)i * CH + lane * 4);
    floatx4 w0 = *reinterpret_cast<const floatx4*>(Wc + lane * 8);
    floatx4 w1 = *reinterpret_cast<const floatx4*>(Wc + lane * 8 + 4);
    float a0 = xv.x * w0.x + xv.y * w0.z + xv.z * w1.x + xv.w * w1.z;
    float a1 = xv.x * w0.y + xv.y * w0.w + xv.z * w1.y + xv.w * w1.w;
    a0 = wave_sum(a0);
    a1 = wave_sum(a1);
    if (lane == 0) { out[2 * i] = a0; out[2 * i + 1] = a1; }
}

__global__ void sparse4b_k(const float* __restrict__ x, const float* __restrict__ W4,
                           float* __restrict__ out, const int2* __restrict__ buckets,
                           const int2* __restrict__ desc, const int* __restrict__ nchunks) {
    int nc = *nchunks;
    int wid = threadIdx.x >> 6, lane = threadIdx.x & 63;
    for (int m = blockIdx.x; m < nc; m += gridDim.x) {
        int2 d = desc[m];
        int k = d.y >> 8, len = d.y & 255;
        const float* Wk = W4 + (size_t)k * CH * 2;
        floatx4 w0 = *reinterpret_cast<const floatx4*>(Wk + lane * 8);
        floatx4 w1 = *reinterpret_cast<const floatx4*>(Wk + lane * 8 + 4);
        for (int p = wid; p < len; p += 4) {
            int2 pr = buckets[d.x + p];
            floatx4 xv = *reinterpret_cast<const floatx4*>(x + (size_t)pr.y * CH + lane * 4);
            float a0 = xv.x * w0.x + xv.y * w0.z + xv.z * w1.x + xv.w * w1.z;
            float a1 = xv.x * w0.y + xv.y * w0.w + xv.z * w1.y + xv.w * w1.w;
            a0 = wave_sum(a0);
            a1 = wave_sum(a1);
            if (lane == 0) {
                atomicAdd(&out[2 * pr.x], a0);
                atomicAdd(&out[2 * pr.x + 1], a1);
            }
        }
    }
}

extern "C" void kernel_launch(void* const* d_in, const int* in_sizes, int n_in,
                              void* d_out, int out_size, void* d_ws, size_t ws_size,
                              hipStream_t stream) {
    const int* coords = (const int*)d_in[0];
    const float* feats = (const float*)d_in[1];
    const float* W1 = (const float*)d_in[2];
    const float* W2 = (const float*)d_in[3];
    const float* W3 = (const float*)d_in[4];
    const float* W4 = (const float*)d_in[5];
    float* out = (float*)d_out;
    int n = in_sizes[0] / 3;

    char* ws = (char*)d_ws;
    auto alloc = [&](size_t bytes) -> void* {
        void* p = (void*)ws;
        ws += (bytes + 255) & ~(size_t)255;
        return p;
    };
    unsigned* hkeys = (unsigned*)alloc((size_t)HASH_SIZE * 4);
    int* hvals = (int*)alloc((size_t)HASH_SIZE * 4);
    int* kcount = (int*)alloc(27 * 4);
    int* nchunks = (int*)alloc(4);
    int ndesc = 27 * ((n + PCH - 1) / PCH);
    int2* desc = (int2*)alloc(sizeof(int2) * (size_t)ndesc);
    int2* buckets = (int2*)alloc(sizeof(int2) * 27 * (size_t)n);
    unsigned short* Whi2 = (unsigned short*)alloc(65536 * 2);
    unsigned short* Wlo2 = (unsigned short*)alloc(65536 * 2);
    unsigned short* Whi3 = (unsigned short*)alloc(65536 * 2);
    unsigned short* Wlo3 = (unsigned short*)alloc(65536 * 2);
    float* x1 = (float*)alloc((size_t)n * CH * 4);
    float* x2 = (float*)alloc((size_t)n * CH * 4);

    hipMemsetAsync(hkeys, 0xFF, (size_t)HASH_SIZE * 4, stream);
    hipMemsetAsync(kcount, 0, 27 * 4, stream);

    hash_insert_k<<<(n + 255) / 256, 256, 0, stream>>>(coords, n, hkeys, hvals);
    neighbor_buckets_k<<<(n * 27 + 255) / 256, 256, 0, stream>>>(coords, n, hkeys, hvals,
                                                                 buckets, kcount);
    chunk_desc_k<<<1, 256, 0, stream>>>(kcount, n, desc, nchunks);
    prep_w_k<<<256, 256, 0, stream>>>(W2, Whi2, Wlo2);
    prep_w_k<<<256, 256, 0, stream>>>(W3, Whi3, Wlo3);

    int mtiles = (n + 63) / 64;

    // layer 1: 2 -> 256
    dense1_k<<<(n * CH + 255) / 256, 256, 0, stream>>>(feats, W1 + 13 * 2 * CH, x1, n);
    sparse1b_k<<<1024, 256, 0, stream>>>(feats, W1, x1, buckets, desc, nchunks);

    // layer 2: 256 -> 256
    dense_mid_mfma_k<<<mtiles, 256, 0, stream>>>(x1, Whi2, Wlo2, x2, n);
    sparse_mid2_k<<<1024, 256, 0, stream>>>(x1, W2, x2, buckets, desc, nchunks);

    // layer 3: 256 -> 256
    dense_mid_mfma_k<<<mtiles, 256, 0, stream>>>(x2, Whi3, Wlo3, x1, n);
    sparse_mid2_k<<<1024, 256, 0, stream>>>(x2, W3, x1, buckets, desc, nchunks);

    // layer 4: 256 -> 2
    dense4_k<<<(n + 3) / 4, 256, 0, stream>>>(x1, W4 + 13 * CH * 2, out, n);
    sparse4b_k<<<512, 256, 0, stream>>>(x1, W4, out, buckets, desc, nchunks);
}

// Round 3
// 427.364 us; speedup vs baseline: 2.6225x; 1.0007x over previous
//
#include <hip/hip_runtime.h>

#define HASH_BITS 19
#define HASH_SIZE (1u << HASH_BITS)
#define HASH_MASK (HASH_SIZE - 1)
#define EMPTY_KEY 0xFFFFFFFFu
#define CH 256
#define PCH 32  // pairs per chunk in bucketed sparse kernels

typedef __attribute__((ext_vector_type(8))) short short8;
typedef __attribute__((ext_vector_type(4))) float floatx4;

// split fp32 -> bf16 hi + bf16 lo (x ~= hi + lo, each RTN-even)
__device__ inline void bf16_split(float x, unsigned short& hi, unsigned short& lo) {
    unsigned u = __float_as_uint(x);
    unsigned r = u + (0x7FFFu + ((u >> 16) & 1u));
    hi = (unsigned short)(r >> 16);
    float hif = __uint_as_float(((unsigned)hi) << 16);
    float res = x - hif;
    unsigned v = __float_as_uint(res);
    unsigned rv = v + (0x7FFFu + ((v >> 16) & 1u));
    lo = (unsigned short)(rv >> 16);
}

__device__ inline void split8_pack(const float* xa, uint4& hv, uint4& lv) {
    unsigned short h[8], l[8];
#pragma unroll
    for (int q = 0; q < 8; ++q) bf16_split(xa[q], h[q], l[q]);
    hv.x = (unsigned)h[0] | ((unsigned)h[1] << 16);
    hv.y = (unsigned)h[2] | ((unsigned)h[3] << 16);
    hv.z = (unsigned)h[4] | ((unsigned)h[5] << 16);
    hv.w = (unsigned)h[6] | ((unsigned)h[7] << 16);
    lv.x = (unsigned)l[0] | ((unsigned)l[1] << 16);
    lv.y = (unsigned)l[2] | ((unsigned)l[3] << 16);
    lv.z = (unsigned)l[4] | ((unsigned)l[5] << 16);
    lv.w = (unsigned)l[6] | ((unsigned)l[7] << 16);
}

// ---------------- hash build (also emits per-point linear key) ----------------
__global__ void hash_insert_k(const int* __restrict__ coords, int n,
                              unsigned* __restrict__ hkeys, int* __restrict__ hvals,
                              unsigned* __restrict__ keys) {
    int i = blockIdx.x * blockDim.x + threadIdx.x;
    if (i >= n) return;
    unsigned cx = (unsigned)(coords[3 * i + 0] + 1);
    unsigned cy = (unsigned)(coords[3 * i + 1] + 1);
    unsigned cz = (unsigned)(coords[3 * i + 2] + 1);
    unsigned key = (cx * 258u + cy) * 258u + cz;
    keys[i] = key;
    unsigned h = (key * 2654435761u) & HASH_MASK;
    while (true) {
        unsigned prev = atomicCAS(&hkeys[h], EMPTY_KEY, key);
        if (prev == EMPTY_KEY) { hvals[h] = i; return; }
        h = (h + 1) & HASH_MASK;
    }
}

// ---------------- neighbor pairs: one thread per point, 26-way MLP ----------------
__global__ void neighbor_all_k(const unsigned* __restrict__ keys, int n,
                               const unsigned* __restrict__ hkeys,
                               const int* __restrict__ hvals,
                               int2* __restrict__ buckets, int* __restrict__ kcount) {
    int i = blockIdx.x * blockDim.x + threadIdx.x;
    if (i >= n) return;
    unsigned key = keys[i];
    unsigned nk[27], hh[27], v[27];
#pragma unroll
    for (int k = 0; k < 27; ++k) {
        int dx = k / 9 - 1, dy = (k / 3) % 3 - 1, dz = k % 3 - 1;
        nk[k] = (unsigned)((int)key + (dx * 258 + dy) * 258 + dz);
        hh[k] = (nk[k] * 2654435761u) & HASH_MASK;
    }
#pragma unroll
    for (int k = 0; k < 27; ++k) v[k] = hkeys[hh[k]];   // 27 independent loads in flight
#pragma unroll
    for (int k = 0; k < 27; ++k) {
        if (k == 13) continue;  // center handled densely
        unsigned cur = v[k], h = hh[k];
        while (true) {
            if (cur == nk[k]) {
                int j = hvals[h];
                int pos = atomicAdd(&kcount[k], 1);
                buckets[(size_t)k * n + pos] = make_int2(i, j);
                break;
            }
            if (cur == EMPTY_KEY) break;
            h = (h + 1) & HASH_MASK;
            cur = hkeys[h];
        }
    }
}

// ---------------- chunk descriptors: (start, k<<8|len) per <=PCH-pair chunk ----------------
__global__ void chunk_desc_k(const int* __restrict__ kcount, int n,
                             int2* __restrict__ desc, int* __restrict__ nchunks) {
    __shared__ int offs[28];
    int t = threadIdx.x;
    if (t == 0) {
        int acc = 0;
        for (int k = 0; k < 27; ++k) { offs[k] = acc; acc += (kcount[k] + PCH - 1) / PCH; }
        offs[27] = acc;
        *nchunks = acc;
    }
    __syncthreads();
    if (t < 27) {
        int cnt = kcount[t];
        int o = offs[t];
        for (int c = 0; c * PCH < cnt; ++c) {
            int len = min(PCH, cnt - c * PCH);
            desc[o + c] = make_int2(t * n + c * PCH, (t << 8) | len);
        }
    }
}

// ---------------- pre-split ALL 27 W slices into MFMA-fragment-ordered bf16 image ----------
// image layout: [k(27)][kk(8)][nt(16)][lane(64)][j(8)] shorts
// cin = kk*32 + (lane>>4)*8 + j,  cout = nt*16 + (lane&15)
__global__ void prep_w_all_k(const float* __restrict__ W, unsigned short* __restrict__ Whi,
                             unsigned short* __restrict__ Wlo) {
    int tt = blockIdx.x * 256 + threadIdx.x;
    if (tt >= 27 * 65536) return;
    int k = tt >> 16, rem = tt & 65535, cin = rem >> 8, cout = rem & 255;
    float w = W[tt];
    unsigned short hb, lb;
    bf16_split(w, hb, lb);
    int kk = cin >> 5, kg = (cin >> 3) & 3, j = cin & 7, nt = cout >> 4, lc = cout & 15;
    size_t idx = ((((size_t)(k * 8 + kk) * 16 + nt) * 64) + kg * 16 + lc) * 8 + j;
    Whi[idx] = hb;
    Wlo[idx] = lb;
}

// ---------------- layer 1: Cin=2 -> 256, dense center ----------------
__global__ void dense1_k(const float* __restrict__ x, const float* __restrict__ Wc,
                         float* __restrict__ out, int n) {
    int t = blockIdx.x * blockDim.x + threadIdx.x;
    if (t >= n * CH) return;
    int i = t >> 8, co = t & 255;
    float2 xv = *reinterpret_cast<const float2*>(x + 2 * i);
    out[t] = fmaf(xv.x, Wc[co], xv.y * Wc[CH + co]);
}

__global__ void sparse1b_k(const float* __restrict__ feats, const float* __restrict__ W1,
                           float* __restrict__ out, const int2* __restrict__ buckets,
                           const int2* __restrict__ desc, const int* __restrict__ nchunks) {
    __shared__ float xs[PCH][2];
    __shared__ int ii[PCH];
    int nc = *nchunks;
    int t = threadIdx.x;
    for (int m = blockIdx.x; m < nc; m += gridDim.x) {
        int2 d = desc[m];
        int k = d.y >> 8, len = d.y & 255;
        if (t < PCH) {
            if (t < len) {
                int2 pr = buckets[d.x + t];
                ii[t] = pr.x;
                xs[t][0] = feats[2 * pr.y];
                xs[t][1] = feats[2 * pr.y + 1];
            } else {
                ii[t] = -1;
                xs[t][0] = 0.f; xs[t][1] = 0.f;
            }
        }
        __syncthreads();
        const float* Wk = W1 + (size_t)k * 2 * CH;
        float w0 = Wk[t], w1 = Wk[CH + t];
#pragma unroll
        for (int p = 0; p < PCH; ++p) {
            int i = ii[p];
            if (i >= 0) atomicAdd(&out[(size_t)i * CH + t], fmaf(xs[p][0], w0, xs[p][1] * w1));
        }
        __syncthreads();
    }
}

// ---------------- mid layers dense center: split-bf16 3-pass MFMA ----------------
__global__ __launch_bounds__(256) void dense_mid_mfma_k(
        const float* __restrict__ x,
        const unsigned short* __restrict__ Whi,
        const unsigned short* __restrict__ Wlo,
        float* __restrict__ out, int n) {
    __shared__ unsigned short As_hi[4 * 64 * 8];
    __shared__ unsigned short As_lo[4 * 64 * 8];
    __shared__ unsigned short Bs_hi[16 * 64 * 8];
    __shared__ unsigned short Bs_lo[16 * 64 * 8];
    int t = threadIdx.x;
    int wid = t >> 6, lane = t & 63;
    int i0 = blockIdx.x * 64;

    floatx4 acc[4][4];
#pragma unroll
    for (int a = 0; a < 4; ++a)
#pragma unroll
        for (int b = 0; b < 4; ++b) acc[a][b] = floatx4{0.f, 0.f, 0.f, 0.f};

    int ar = t >> 2;   // row 0..63 in tile
    int akg = t & 3;   // k-group
    int abase = ((ar >> 4) * 64 + (akg * 16 + (ar & 15))) * 8;
    const float* xrow = x + (size_t)(i0 + ar) * CH + akg * 8;
    bool arow_ok = (i0 + ar) < n;

    for (int kk = 0; kk < 8; ++kk) {
        // ---- stage A: load 8 fp32, split to hi/lo, write fragment-ordered ----
        float xa[8];
        if (arow_ok) {
            floatx4 v0 = *(const floatx4*)(xrow + kk * 32);
            floatx4 v1 = *(const floatx4*)(xrow + kk * 32 + 4);
            xa[0] = v0.x; xa[1] = v0.y; xa[2] = v0.z; xa[3] = v0.w;
            xa[4] = v1.x; xa[5] = v1.y; xa[6] = v1.z; xa[7] = v1.w;
        } else {
#pragma unroll
            for (int q = 0; q < 8; ++q) xa[q] = 0.f;
        }
        uint4 hv, lv;
        split8_pack(xa, hv, lv);
        *(uint4*)&As_hi[abase] = hv;
        *(uint4*)&As_lo[abase] = lv;
        // ---- stage B: linear copy of pre-ordered slab (16KB hi + 16KB lo) ----
        {
            const uint4* gh = (const uint4*)(Whi + kk * 8192);
            const uint4* gl = (const uint4*)(Wlo + kk * 8192);
            uint4* sh = (uint4*)Bs_hi;
            uint4* sl = (uint4*)Bs_lo;
#pragma unroll
            for (int c = 0; c < 4; ++c) {
                sh[t + c * 256] = gh[t + c * 256];
                sl[t + c * 256] = gl[t + c * 256];
            }
        }
        __syncthreads();
        short8 bh[4], bl[4];
#pragma unroll
        for (int nt = 0; nt < 4; ++nt) {
            int g = ((wid * 4 + nt) * 64 + lane) * 8;
            bh[nt] = *(const short8*)&Bs_hi[g];
            bl[nt] = *(const short8*)&Bs_lo[g];
        }
#pragma unroll
        for (int mt = 0; mt < 4; ++mt) {
            short8 ah = *(const short8*)&As_hi[(mt * 64 + lane) * 8];
            short8 al = *(const short8*)&As_lo[(mt * 64 + lane) * 8];
#pragma unroll
            for (int nt = 0; nt < 4; ++nt) {
                acc[mt][nt] = __builtin_amdgcn_mfma_f32_16x16x32_bf16(ah, bh[nt], acc[mt][nt], 0, 0, 0);
                acc[mt][nt] = __builtin_amdgcn_mfma_f32_16x16x32_bf16(al, bh[nt], acc[mt][nt], 0, 0, 0);
                acc[mt][nt] = __builtin_amdgcn_mfma_f32_16x16x32_bf16(ah, bl[nt], acc[mt][nt], 0, 0, 0);
            }
        }
        __syncthreads();
    }
    // epilogue: D row=(lane>>4)*4+reg, col=lane&15
    int r0 = (lane >> 4) * 4, c0 = lane & 15;
#pragma unroll
    for (int mt = 0; mt < 4; ++mt)
#pragma unroll
        for (int r = 0; r < 4; ++r) {
            int row = i0 + mt * 16 + r0 + r;
            if (row < n) {
#pragma unroll
                for (int nt = 0; nt < 4; ++nt)
                    out[(size_t)row * CH + wid * 64 + nt * 16 + c0] = acc[mt][nt][r];
            }
        }
}

// ---------------- mid layers sparse: 32 gathered rows per chunk, 3-pass MFMA ----------------
__global__ __launch_bounds__(256) void sparse_mid_mfma_k(
        const float* __restrict__ x,
        const unsigned short* __restrict__ Whi,
        const unsigned short* __restrict__ Wlo,
        float* __restrict__ out, const int2* __restrict__ buckets,
        const int2* __restrict__ desc, const int* __restrict__ nchunks) {
    // A image: [kk(8)][mt(2)][lane(64)][j(8)]
    __shared__ unsigned short As_hi[8192];
    __shared__ unsigned short As_lo[8192];
    __shared__ int ii[PCH];
    int nc = *nchunks;
    int t = threadIdx.x;
    int wid = t >> 6, lane = t & 63;
    int r = t >> 3, kk0 = t & 7;          // 8 threads per gathered row
    int mt_s = r >> 4, rl = r & 15;
    for (int m = blockIdx.x; m < nc; m += gridDim.x) {
        int2 d = desc[m];
        int k = d.y >> 8, len = d.y & 255;
        // ---- stage A (full K=256 for 32 rows), split hi/lo ----
        if (r < len) {
            int2 pr = buckets[d.x + r];
            if (kk0 == 0) ii[r] = pr.x;
            const float* src = x + (size_t)pr.y * CH + kk0 * 32;
#pragma unroll
            for (int kg = 0; kg < 4; ++kg) {
                float xa[8];
                floatx4 v0 = *(const floatx4*)(src + kg * 8);
                floatx4 v1 = *(const floatx4*)(src + kg * 8 + 4);
                xa[0] = v0.x; xa[1] = v0.y; xa[2] = v0.z; xa[3] = v0.w;
                xa[4] = v1.x; xa[5] = v1.y; xa[6] = v1.z; xa[7] = v1.w;
                uint4 hv, lv;
                split8_pack(xa, hv, lv);
                int ab = ((kk0 * 2 + mt_s) * 64 + kg * 16 + rl) * 8;
                *(uint4*)&As_hi[ab] = hv;
                *(uint4*)&As_lo[ab] = lv;
            }
        } else {
            if (kk0 == 0) ii[r] = -1;
            uint4 z = {0, 0, 0, 0};
#pragma unroll
            for (int kg = 0; kg < 4; ++kg) {
                int ab = ((kk0 * 2 + mt_s) * 64 + kg * 16 + rl) * 8;
                *(uint4*)&As_hi[ab] = z;
                *(uint4*)&As_lo[ab] = z;
            }
        }
        __syncthreads();
        floatx4 acc[2][4];
#pragma unroll
        for (int a = 0; a < 2; ++a)
#pragma unroll
            for (int b = 0; b < 4; ++b) acc[a][b] = floatx4{0.f, 0.f, 0.f, 0.f};
        for (int kk = 0; kk < 8; ++kk) {
            short8 ah0 = *(const short8*)&As_hi[((kk * 2 + 0) * 64 + lane) * 8];
            short8 al0 = *(const short8*)&As_lo[((kk * 2 + 0) * 64 + lane) * 8];
            short8 ah1 = *(const short8*)&As_hi[((kk * 2 + 1) * 64 + lane) * 8];
            short8 al1 = *(const short8*)&As_lo[((kk * 2 + 1) * 64 + lane) * 8];
#pragma unroll
            for (int q = 0; q < 4; ++q) {
                int nt = wid * 4 + q;
                size_t off = (((size_t)(k * 8 + kk) * 16 + nt) * 64 + lane) * 8;
                short8 bh = *(const short8*)&Whi[off];   // B direct global->VGPR (used once)
                short8 bl = *(const short8*)&Wlo[off];
                acc[0][q] = __builtin_amdgcn_mfma_f32_16x16x32_bf16(ah0, bh, acc[0][q], 0, 0, 0);
                acc[0][q] = __builtin_amdgcn_mfma_f32_16x16x32_bf16(al0, bh, acc[0][q], 0, 0, 0);
                acc[0][q] = __builtin_amdgcn_mfma_f32_16x16x32_bf16(ah0, bl, acc[0][q], 0, 0, 0);
                acc[1][q] = __builtin_amdgcn_mfma_f32_16x16x32_bf16(ah1, bh, acc[1][q], 0, 0, 0);
                acc[1][q] = __builtin_amdgcn_mfma_f32_16x16x32_bf16(al1, bh, acc[1][q], 0, 0, 0);
                acc[1][q] = __builtin_amdgcn_mfma_f32_16x16x32_bf16(ah1, bl, acc[1][q], 0, 0, 0);
            }
        }
        // ---- epilogue: atomic accumulate ----
        int r0 = (lane >> 4) * 4, c0 = lane & 15;
#pragma unroll
        for (int mt = 0; mt < 2; ++mt)
#pragma unroll
            for (int rr = 0; rr < 4; ++rr) {
                int row = mt * 16 + r0 + rr;
                int i = ii[row];
                if (i >= 0) {
#pragma unroll
                    for (int q = 0; q < 4; ++q)
                        atomicAdd(&out[(size_t)i * CH + wid * 64 + q * 16 + c0], acc[mt][q][rr]);
                }
            }
        __syncthreads();
    }
}

// ---------------- layer 4: 256 -> 2 ----------------
__device__ inline float wave_sum(float v) {
    for (int off = 32; off; off >>= 1) v += __shfl_xor(v, off);
    return v;
}

__global__ void dense4_k(const float* __restrict__ x, const float* __restrict__ Wc,
                         float* __restrict__ out, int n) {
    int wid = threadIdx.x >> 6, lane = threadIdx.x & 63;
    int i = blockIdx.x * 4 + wid;
    if (i >= n) return;
    floatx4 xv = *reinterpret_cast<const floatx4*>(x + (size_t)i * CH + lane * 4);
    floatx4 w0 = *reinterpret_cast<const floatx4*>(Wc + lane * 8);
    floatx4 w1 = *reinterpret_cast<const floatx4*>(Wc + lane * 8 + 4);
    float a0 = xv.x * w0.x + xv.y * w0.z + xv.z * w1.x + xv.w * w1.z;
    float a1 = xv.x * w0.y + xv.y * w0.w + xv.z * w1.y + xv.w * w1.w;
    a0 = wave_sum(a0);
    a1 = wave_sum(a1);
    if (lane == 0) { out[2 * i] = a0; out[2 * i + 1] = a1; }
}

__global__ void sparse4b_k(const float* __restrict__ x, const float* __restrict__ W4,
                           float* __restrict__ out, const int2* __restrict__ buckets,
                           const int2* __restrict__ desc, const int* __restrict__ nchunks) {
    int nc = *nchunks;
    int wid = threadIdx.x >> 6, lane = threadIdx.x & 63;
    for (int m = blockIdx.x; m < nc; m += gridDim.x) {
        int2 d = desc[m];
        int k = d.y >> 8, len = d.y & 255;
        const float* Wk = W4 + (size_t)k * CH * 2;
        floatx4 w0 = *reinterpret_cast<const floatx4*>(Wk + lane * 8);
        floatx4 w1 = *reinterpret_cast<const floatx4*>(Wk + lane * 8 + 4);
        for (int p = wid; p < len; p += 4) {
            int2 pr = buckets[d.x + p];
            floatx4 xv = *reinterpret_cast<const floatx4*>(x + (size_t)pr.y * CH + lane * 4);
            float a0 = xv.x * w0.x + xv.y * w0.z + xv.z * w1.x + xv.w * w1.z;
            float a1 = xv.x * w0.y + xv.y * w0.w + xv.z * w1.y + xv.w * w1.w;
            a0 = wave_sum(a0);
            a1 = wave_sum(a1);
            if (lane == 0) {
                atomicAdd(&out[2 * pr.x], a0);
                atomicAdd(&out[2 * pr.x + 1], a1);
            }
        }
    }
}

extern "C" void kernel_launch(void* const* d_in, const int* in_sizes, int n_in,
                              void* d_out, int out_size, void* d_ws, size_t ws_size,
                              hipStream_t stream) {
    const int* coords = (const int*)d_in[0];
    const float* feats = (const float*)d_in[1];
    const float* W1 = (const float*)d_in[2];
    const float* W2 = (const float*)d_in[3];
    const float* W3 = (const float*)d_in[4];
    const float* W4 = (const float*)d_in[5];
    float* out = (float*)d_out;
    int n = in_sizes[0] / 3;

    char* ws = (char*)d_ws;
    auto alloc = [&](size_t bytes) -> void* {
        void* p = (void*)ws;
        ws += (bytes + 255) & ~(size_t)255;
        return p;
    };
    unsigned* hkeys = (unsigned*)alloc((size_t)HASH_SIZE * 4);
    int* hvals = (int*)alloc((size_t)HASH_SIZE * 4);
    unsigned* keys = (unsigned*)alloc((size_t)n * 4);
    int* kcount = (int*)alloc(27 * 4);
    int* nchunks = (int*)alloc(4);
    int ndesc = 27 * ((n + PCH - 1) / PCH);
    int2* desc = (int2*)alloc(sizeof(int2) * (size_t)ndesc);
    int2* buckets = (int2*)alloc(sizeof(int2) * 27 * (size_t)n);
    unsigned short* Whi2 = (unsigned short*)alloc((size_t)27 * 65536 * 2);
    unsigned short* Wlo2 = (unsigned short*)alloc((size_t)27 * 65536 * 2);
    unsigned short* Whi3 = (unsigned short*)alloc((size_t)27 * 65536 * 2);
    unsigned short* Wlo3 = (unsigned short*)alloc((size_t)27 * 65536 * 2);
    float* x1 = (float*)alloc((size_t)n * CH * 4);
    float* x2 = (float*)alloc((size_t)n * CH * 4);

    hipMemsetAsync(hkeys, 0xFF, (size_t)HASH_SIZE * 4, stream);
    hipMemsetAsync(kcount, 0, 27 * 4, stream);

    hash_insert_k<<<(n + 255) / 256, 256, 0, stream>>>(coords, n, hkeys, hvals, keys);
    neighbor_all_k<<<(n + 255) / 256, 256, 0, stream>>>(keys, n, hkeys, hvals, buckets, kcount);
    chunk_desc_k<<<1, 256, 0, stream>>>(kcount, n, desc, nchunks);
    prep_w_all_k<<<(27 * 65536) / 256, 256, 0, stream>>>(W2, Whi2, Wlo2);
    prep_w_all_k<<<(27 * 65536) / 256, 256, 0, stream>>>(W3, Whi3, Wlo3);

    int mtiles = (n + 63) / 64;

    // layer 1: 2 -> 256
    dense1_k<<<(n * CH + 255) / 256, 256, 0, stream>>>(feats, W1 + 13 * 2 * CH, x1, n);
    sparse1b_k<<<1024, 256, 0, stream>>>(feats, W1, x1, buckets, desc, nchunks);

    // layer 2: 256 -> 256
    dense_mid_mfma_k<<<mtiles, 256, 0, stream>>>(x1, Whi2 + 13 * 65536, Wlo2 + 13 * 65536, x2, n);
    sparse_mid_mfma_k<<<512, 256, 0, stream>>>(x1, Whi2, Wlo2, x2, buckets, desc, nchunks);

    // layer 3: 256 -> 256
    dense_mid_mfma_k<<<mtiles, 256, 0, stream>>>(x2, Whi3 + 13 * 65536, Wlo3 + 13 * 65536, x1, n);
    sparse_mid_mfma_k<<<512, 256, 0, stream>>>(x2, Whi3, Wlo3, x1, buckets, desc, nchunks);

    // layer 4: 256 -> 2
    dense4_k<<<(n + 3) / 4, 256, 0, stream>>>(x1, W4 + 13 * CH * 2, out, n);
    sparse4b_k<<<512, 256, 0, stream>>>(x1, W4, out, buckets, desc, nchunks);
}